// Round 7
// baseline (1838.759 us; speedup 1.0000x reference)
//
#include <hip/hip_runtime.h>
#include <hip/hip_bf16.h>
#include <math.h>

#define NN 3
#define BB 4
#define CC 256
#define C2 512
#define HH 40
#define WW 40
#define PP 1600
#define NBB 12                  // NN*BB
#define NODESZ (NBB*CC*PP)      // 4,915,200
#define TO 16                   // theta: output channels per block
#define PAD 1764                // 42*42 padded pixels

typedef short short8 __attribute__((ext_vector_type(8)));
typedef float f32x4 __attribute__((ext_vector_type(4)));
typedef unsigned short ushort_t;
typedef unsigned int uint_t;

__device__ __forceinline__ ushort_t f2bf(float x) {
  union { float f; uint_t u; } v; v.f = x;
  uint_t r = v.u + 0x7fff + ((v.u >> 16) & 1);
  return (ushort_t)(r >> 16);
}

__device__ __forceinline__ void async_ld16(const ushort_t* g, ushort_t* l) {
  __builtin_amdgcn_global_load_lds(
      (const __attribute__((address_space(1))) uint_t*)g,
      (__attribute__((address_space(3))) uint_t*)l, 16, 0, 0);
}

__global__ void k_copy(const float* __restrict__ in, float* __restrict__ out) {
  int i = blockIdx.x * 256 + threadIdx.x;
  out[i] = in[i];
}

// th_t[nb][p][c] (bf16) = tb[o] + sum_c tw[o,c] * nodes[nb,c,p]
__global__ void k_theta(const float* __restrict__ nodes, const float* __restrict__ tw,
                        const float* __restrict__ tb, ushort_t* __restrict__ th_t) {
  __shared__ float w[TO * CC];
  int t = threadIdx.x;
  int nb = blockIdx.y / (CC / TO);
  int o0 = (blockIdx.y % (CC / TO)) * TO;
  for (int i = t; i < TO * CC; i += 320) w[i] = tw[(o0 + (i >> 8)) * CC + (i & 255)];
  __syncthreads();
  int p = blockIdx.x * 320 + t;
  const float* src = nodes + nb * CC * PP + p;
  float acc[TO];
#pragma unroll
  for (int o = 0; o < TO; ++o) acc[o] = tb[o0 + o];
  for (int c = 0; c < CC; c += 4) {
    float v0 = src[c * PP], v1 = src[(c + 1) * PP], v2 = src[(c + 2) * PP], v3 = src[(c + 3) * PP];
#pragma unroll
    for (int o = 0; o < TO; ++o) {
      const float4 ww = *(const float4*)(w + o * CC + c);
      acc[o] += ww.x * v0 + ww.y * v1 + ww.z * v2 + ww.w * v3;
    }
  }
  size_t base = ((size_t)nb * PP + p) * CC + o0;
#pragma unroll
  for (int o = 0; o < TO; o += 2) {
    uint_t lo = f2bf(acc[o]), hi = f2bf(acc[o + 1]);
    *(uint_t*)&th_t[base + o] = lo | (hi << 16);
  }
}

// nodes [12][256][1600] fp32 -> nodes_bf_t [12][1600][256] bf16 (transpose)
__global__ void k_to_bf_t(const float* __restrict__ src, ushort_t* __restrict__ dst) {
  __shared__ float tile[32][33];
  int nb = blockIdx.z;
  int c0 = blockIdx.y * 32;
  int pp0 = blockIdx.x * 32;
  int tx = threadIdx.x & 31, ty = threadIdx.x >> 5;
#pragma unroll
  for (int i = 0; i < 4; ++i)
    tile[ty + 8 * i][tx] = src[((size_t)nb * CC + c0 + ty + 8 * i) * PP + pp0 + tx];
  __syncthreads();
#pragma unroll
  for (int i = 0; i < 4; ++i)
    dst[((size_t)nb * PP + pp0 + ty + 8 * i) * CC + c0 + tx] = f2bf(tile[tx][ty + 8 * i]);
}

// v_all[e][b][c][p] (bf16) = nodes[recv(e),b,c,p] + nodes[send(e),b,c,p]
__global__ void k_prep_v(const float* __restrict__ nodes, ushort_t* __restrict__ v_all) {
  int i = blockIdx.x * 256 + threadIdx.x;   // 6*4*256*1600
  int eb = i / (CC * PP);
  int rem = i - eb * (CC * PP);
  int e = eb >> 2, b = eb & 3;
  int n = e >> 1, jidx = e & 1;
  int js = jidx + (jidx >= n ? 1 : 0);
  float v = nodes[((size_t)(n * BB + b)) * CC * PP + rem] +
            nodes[((size_t)(js * BB + b)) * CC * PP + rem];
  v_all[i] = f2bf(v);
}

// Barrier-free flash attention. Wave = 16 p-rows, fully independent:
// softmax state (M,L,alpha) in registers (S and O share C-layout row = quad*4+r);
// only LDS use is the per-wave double-buffered P transpose (C->A layout).
// Block = 2 waves (128 thr), grid (50, nb, jidx) = 1200 blocks, all co-resident.
__global__ __launch_bounds__(128, 3) void k_attn_mfma(
    const ushort_t* __restrict__ nodes_bf_t,  // [12][1600][256]
    const ushort_t* __restrict__ th_t,        // [12][1600][256]
    const ushort_t* __restrict__ v_all,       // [6][4][256][1600]
    float* __restrict__ agg_t)                // [2][12][1600][256]
{
  __shared__ ushort_t SpBuf[2][2][16 * 72];   // [wave][buf][row][col(64)+pad8]

  const int t = threadIdx.x;
  const int w = t >> 6;
  const int l = t & 63;
  const int quad = l >> 4;
  const int l16 = l & 15;
  const int p0 = blockIdx.x * 32;
  const int nb = blockIdx.y;
  const int jidx = blockIdx.z;
  const int n = nb >> 2, b = nb & 3;
  const int e = n * 2 + jidx;
  const int js = jidx + (jidx >= n ? 1 : 0);

  const ushort_t* thp = th_t + ((size_t)nb * PP + p0) * CC;
  const ushort_t* ejq = nodes_bf_t + ((size_t)(js * BB + b) * PP) * CC;  // [q][c]
  const ushort_t* vp  = v_all + ((size_t)(e * BB + b) * CC) * PP;        // [c][q]

  // resident A-frags of th for this wave's 16 rows (m = l16)
  short8 Ath[8];
  {
    const ushort_t* arow = thp + (size_t)(16 * w + l16) * CC + quad * 8;
#pragma unroll
    for (int ks = 0; ks < 8; ++ks) Ath[ks] = *(const short8*)(arow + ks * 32);
  }

  float M[4], L[4];
#pragma unroll
  for (int r = 0; r < 4; ++r) { M[r] = -3.0e38f; L[r] = 0.f; }

  f32x4 O[16];
#pragma unroll
  for (int nt = 0; nt < 16; ++nt)
#pragma unroll
    for (int r = 0; r < 4; ++r) O[nt][r] = 0.f;

  int buf = 0;
  for (int q0 = 0; q0 < PP; q0 += 64) {
    // ---- S-GEMM: 16 rows x 64 q-cols, K=256 ----
    f32x4 S[4];
#pragma unroll
    for (int qt = 0; qt < 4; ++qt)
#pragma unroll
      for (int r = 0; r < 4; ++r) S[qt][r] = 0.f;
    const ushort_t* brow = ejq + (size_t)(q0 + l16) * CC + quad * 8;
#pragma unroll
    for (int ks = 0; ks < 8; ++ks) {
#pragma unroll
      for (int qt = 0; qt < 4; ++qt) {
        short8 B = *(const short8*)(brow + (size_t)(qt * 16) * CC + ks * 32);
        S[qt] = __builtin_amdgcn_mfma_f32_16x16x32_bf16(Ath[ks], B, S[qt], 0, 0, 0);
      }
    }
    // ---- in-register online softmax (rows quad*4+r; cols across l16 x 4 tiles) ----
    ushort_t* sw = &SpBuf[w][buf][0];
    float alpha[4];
#pragma unroll
    for (int r = 0; r < 4; ++r) {
      float m = fmaxf(fmaxf(S[0][r], S[1][r]), fmaxf(S[2][r], S[3][r]));
      m = fmaxf(m, __shfl_xor(m, 1));
      m = fmaxf(m, __shfl_xor(m, 2));
      m = fmaxf(m, __shfl_xor(m, 4));
      m = fmaxf(m, __shfl_xor(m, 8));
      float Mn = fmaxf(M[r], m);
      alpha[r] = __expf(M[r] - Mn);
      float e0 = __expf(S[0][r] - Mn), e1 = __expf(S[1][r] - Mn);
      float e2 = __expf(S[2][r] - Mn), e3 = __expf(S[3][r] - Mn);
      float s = e0 + e1 + e2 + e3;
      s += __shfl_xor(s, 1);
      s += __shfl_xor(s, 2);
      s += __shfl_xor(s, 4);
      s += __shfl_xor(s, 8);
      L[r] = L[r] * alpha[r] + s;
      M[r] = Mn;
      ushort_t* row = sw + (quad * 4 + r) * 72 + l16;
      row[0]  = f2bf(e0);
      row[16] = f2bf(e1);
      row[32] = f2bf(e2);
      row[48] = f2bf(e3);
    }
    // ---- rescale O ----
#pragma unroll
    for (int nt = 0; nt < 16; ++nt)
#pragma unroll
      for (int r = 0; r < 4; ++r) O[nt][r] *= alpha[r];
    // ---- P in A-layout (wave-internal LDS; compiler inserts lgkmcnt) ----
    short8 Ap0 = *(const short8*)(sw + l16 * 72 + quad * 8);
    short8 Ap1 = *(const short8*)(sw + l16 * 72 + 32 + quad * 8);
    // ---- PV: O[16 rows][256 ch] ----
    const ushort_t* vrow = vp + (size_t)l16 * PP + q0 + quad * 8;
#pragma unroll
    for (int nt = 0; nt < 16; ++nt) {
      short8 Bv0 = *(const short8*)(vrow + (size_t)(16 * nt) * PP);
      short8 Bv1 = *(const short8*)(vrow + (size_t)(16 * nt) * PP + 32);
      O[nt] = __builtin_amdgcn_mfma_f32_16x16x32_bf16(Ap0, Bv0, O[nt], 0, 0, 0);
      O[nt] = __builtin_amdgcn_mfma_f32_16x16x32_bf16(Ap1, Bv1, O[nt], 0, 0, 0);
    }
    buf ^= 1;
  }
  // ---- epilogue: normalize, store to agg_t[jidx][nb][p][c] ----
  float* ao = agg_t + (((size_t)jidx * NBB + nb) * PP + p0) * CC;
#pragma unroll
  for (int r = 0; r < 4; ++r) {
    float inv = 1.f / L[r];
    float* dst = ao + (size_t)(16 * w + quad * 4 + r) * CC + l16;
#pragma unroll
    for (int nt = 0; nt < 16; ++nt) dst[16 * nt] = O[nt][r] * inv;
  }
}

// ---- conv prep ----

// reorder conv weights [M][512][3][3] fp32 -> [M][9][512] bf16
__global__ void k_wrep(const float* __restrict__ w, ushort_t* __restrict__ wr) {
  int i = blockIdx.x * 256 + threadIdx.x;   // M*9*512
  int ci = i & 511;
  int rest = i >> 9;                        // co*9 + tap
  int tp = rest % 9, co = rest / 9;
  wr[i] = f2bf(w[((size_t)co * 512 + ci) * 9 + tp]);
}

__global__ void k_pad_zero(ushort_t* __restrict__ xpad) {
  int i = blockIdx.x * 256 + threadIdx.x;   // 12*1764*512
  xpad[i] = 0;
}

// interior rows, ch 0..255 <- agg_t[0]+agg_t[1]  (both already [px][c])
__global__ void k_pad_agg(const float* __restrict__ agg_t, ushort_t* __restrict__ xpad) {
  int i = blockIdx.x * 256 + threadIdx.x;   // 12*1600*256
  int c = i & 255;
  int rest = i >> 8;
  int px = rest % PP, nb = rest / PP;
  int y = px / 40, x = px - y * 40;
  size_t src = ((size_t)nb * PP + px) * CC + c;
  float v = agg_t[src] + agg_t[(size_t)NBB * PP * CC + src];
  xpad[((size_t)nb * PAD + (y + 1) * 42 + (x + 1)) * C2 + c] = f2bf(v);
}

// interior rows, ch 256..511 <- transpose of srcA [nb][256][1600]
// MODE 0: val = h[c][px];  MODE 1: val = h[c][px] * r[c][px]
template <int MODE>
__global__ void k_pad_tr(const float* __restrict__ srcA, const float* __restrict__ srcB,
                         ushort_t* __restrict__ xpad) {
  __shared__ float tile[32][33];
  int nb = blockIdx.z;
  int c0 = blockIdx.y * 32;
  int pp0 = blockIdx.x * 32;
  int tx = threadIdx.x & 31, ty = threadIdx.x >> 5;
#pragma unroll
  for (int i = 0; i < 4; ++i) {
    int c = c0 + ty + 8 * i;
    float v = srcA[((size_t)nb * CC + c) * PP + pp0 + tx];
    if (MODE == 1) v *= srcB[((size_t)nb * C2 + c) * PP + pp0 + tx];  // r-gate
    tile[ty + 8 * i][tx] = v;
  }
  __syncthreads();
#pragma unroll
  for (int i = 0; i < 4; ++i) {
    int px = pp0 + ty + 8 * i;
    int y = px / 40, x = px - y * 40;
    xpad[((size_t)nb * PAD + (y + 1) * 42 + (x + 1)) * C2 + CC + c0 + tx] =
        f2bf(tile[tx][ty + 8 * i]);
  }
}

// Implicit-GEMM conv3x3, M=co, N=px(1600), K=9 taps x 512 ci.
// Block: 128co x 128px, 4 waves (2x2), each 64x64 (4x4 16x16x32 frags).
// ACT 0: out = sigmoid(acc+bias) -> gates [nb][512][1600]
// ACT 1: v = tanh(acc+bias); z = zsrc[256+co]; out(nodes) = (1-z)h + z*v
template <int ACT>
__global__ __launch_bounds__(256) void k_conv_mfma(
    const ushort_t* __restrict__ xpad,   // [12][1764][512]
    const ushort_t* __restrict__ wr,     // [M][9*512]
    const float* __restrict__ bias,      // [M]
    const float* __restrict__ zsrc,      // gates (ACT1)
    float* __restrict__ out)
{
  __shared__ ushort_t Asm[128 * 32];
  __shared__ ushort_t Bsm[128 * 32];
  const int t = threadIdx.x;
  const int w = t >> 6, l = t & 63, quad = l >> 4, l16 = l & 15;
  const int nb = blockIdx.z;
  const int m0 = blockIdx.y * 128;
  const int px0 = blockIdx.x * 128;
  const int wm = (w >> 1) * 64, wn = (w & 1) * 64;

  // --- staging source setup (lane l covers rows 32w + l/4 and +16) ---
  const int lr = l >> 2;
  const int swf = (lr ^ (lr >> 2)) & 3;          // fill-side XOR swizzle
  const int lk = ((l & 3) ^ swf) * 8;            // k-part (shorts)
  const ushort_t* wsrc = wr + (size_t)(m0 + 32 * w + lr) * 4608 + lk;
  int pxa = px0 + 32 * w + lr;      if (pxa > 1599) pxa = 1599;
  int pxb = pxa + 16;               if (pxb > 1599) pxb = 1599;
  {
    int d = px0 + 32 * w + 16 + lr; if (d <= 1599) pxb = d;
  }
  const int ya = pxa / 40, xa = pxa - ya * 40;
  const int yb = pxb / 40, xb = pxb - yb * 40;
  const ushort_t* bsrc_a = xpad + ((size_t)nb * PAD + ya * 42 + xa) * C2 + lk;
  const ushort_t* bsrc_b = xpad + ((size_t)nb * PAD + yb * 42 + xb) * C2 + lk;
  ushort_t* Ad0 = Asm + w * 1024;   // wave-uniform LDS base; HW adds lane*16B
  ushort_t* Ad1 = Asm + w * 1024 + 512;
  ushort_t* Bd0 = Bsm + w * 1024;
  ushort_t* Bd1 = Bsm + w * 1024 + 512;

  // --- frag-read swizzle (row&15 == l16 on both A and B) ---
  const int swr = (l16 ^ (l16 >> 2)) & 3;
  const int fk = ((quad ^ swr) * 8);

  f32x4 acc[4][4];
#pragma unroll
  for (int mt = 0; mt < 4; ++mt)
#pragma unroll
    for (int nt = 0; nt < 4; ++nt)
#pragma unroll
      for (int r = 0; r < 4; ++r) acc[mt][nt][r] = 0.f;

  for (int tap = 0; tap < 9; ++tap) {
    const int ky = tap / 3, kx = tap - ky * 3;
    const int boff = (ky * 42 + kx) * C2;
    const ushort_t* wtap = wsrc + tap * 512;
#pragma unroll 1
    for (int c0 = 0; c0 < 512; c0 += 32) {
      __syncthreads();
      async_ld16(wtap + c0, Ad0);
      async_ld16(wtap + 16 * 4608 + c0, Ad1);
      async_ld16(bsrc_a + boff + c0, Bd0);
      async_ld16(bsrc_b + boff + c0, Bd1);
      __syncthreads();
      short8 Af[4], Bf[4];
#pragma unroll
      for (int mt = 0; mt < 4; ++mt)
        Af[mt] = *(const short8*)(Asm + (wm + mt * 16 + l16) * 32 + fk);
#pragma unroll
      for (int nt = 0; nt < 4; ++nt)
        Bf[nt] = *(const short8*)(Bsm + (wn + nt * 16 + l16) * 32 + fk);
#pragma unroll
      for (int mt = 0; mt < 4; ++mt)
#pragma unroll
        for (int nt = 0; nt < 4; ++nt)
          acc[mt][nt] = __builtin_amdgcn_mfma_f32_16x16x32_bf16(Af[mt], Bf[nt], acc[mt][nt], 0, 0, 0);
    }
  }

  // --- epilogue ---
#pragma unroll
  for (int mt = 0; mt < 4; ++mt) {
#pragma unroll
    for (int r = 0; r < 4; ++r) {
      int co = m0 + wm + mt * 16 + quad * 4 + r;
      float bv = bias[co];
#pragma unroll
      for (int nt = 0; nt < 4; ++nt) {
        int px = px0 + wn + nt * 16 + l16;
        if (px >= PP) continue;
        float v = acc[mt][nt][r] + bv;
        if (ACT == 0) {
          out[((size_t)nb * C2 + co) * PP + px] = 1.f / (1.f + __expf(-v));
        } else {
          v = tanhf(v);
          float z = zsrc[((size_t)nb * C2 + CC + co) * PP + px];
          float* hp = out + ((size_t)nb * CC + co) * PP + px;
          float h = *hp;
          *hp = (1.f - z) * h + z * v;
        }
      }
    }
  }
}

extern "C" void kernel_launch(void* const* d_in, const int* in_sizes, int n_in,
                              void* d_out, int out_size, void* d_ws, size_t ws_size,
                              hipStream_t stream) {
  const float* nodes_in = (const float*)d_in[0];
  const float* tw = (const float*)d_in[1];
  const float* tb = (const float*)d_in[2];
  const float* gw = (const float*)d_in[3];
  const float* gb = (const float*)d_in[4];
  const float* cw = (const float*)d_in[5];
  const float* cb = (const float*)d_in[6];

  float* nodes = (float*)d_out;                      // fp32 state [12][256][1600]
  char* ws = (char*)d_ws;
  // ---- layout (ws >= 98.3 MB, proven in round 0/2) ----
  // attn phase: R0 nodes_bf_t 9.83 | R1 th_t 9.83 | R2 v_all 19.66 | R3 agg_t 39.32
  // conv phase: R1+R2 xh_pad 21.68 | R3 gates 39.32
  // persistent:  78.64.. w_g_r 4.72 | 83.36.. w_c_r 2.36   (pass-invariant)
  ushort_t* nodes_bf_t = (ushort_t*)ws;
  ushort_t* th_t  = (ushort_t*)(ws + 9830400);
  ushort_t* v_all = (ushort_t*)(ws + 19660800);
  float*    agg_t = (float*)(ws + 39321600);
  ushort_t* xh_pad = (ushort_t*)(ws + 9830400);      // 12*1764*512*2 = 21,676,032
  float*    gates = (float*)(ws + 39321600);
  ushort_t* w_g_r = (ushort_t*)(ws + 78643200);      // 4,718,592 B
  ushort_t* w_c_r = (ushort_t*)(ws + 83361792);      // 2,359,296 B (ends 85.7 MB)

  k_copy<<<NODESZ / 256, 256, 0, stream>>>(nodes_in, nodes);
  k_wrep<<<(C2 * 9 * C2) / 256, 256, 0, stream>>>(gw, w_g_r);
  k_wrep<<<(CC * 9 * C2) / 256, 256, 0, stream>>>(cw, w_c_r);
  for (int pass = 0; pass < 2; ++pass) {
    // ---- attention ----
    k_theta<<<dim3(5, NBB * (CC / TO)), 320, 0, stream>>>(nodes, tw, tb, th_t);
    k_to_bf_t<<<dim3(50, 8, NBB), 256, 0, stream>>>(nodes, nodes_bf_t);
    k_prep_v<<<(2 * NODESZ) / 256, 256, 0, stream>>>(nodes, v_all);
    k_attn_mfma<<<dim3(50, NBB, 2), 128, 0, stream>>>(nodes_bf_t, th_t, v_all, agg_t);
    // ---- conv prep (attn scratch now dead) ----
    k_pad_zero<<<(NBB * PAD * C2) / 256, 256, 0, stream>>>(xh_pad);
    k_pad_agg<<<(NBB * PP * CC) / 256, 256, 0, stream>>>(agg_t, xh_pad);
    k_pad_tr<0><<<dim3(50, 8, NBB), 256, 0, stream>>>(nodes, nullptr, xh_pad);
    // ---- gates conv ----
    k_conv_mfma<0><<<dim3(13, 4, NBB), 256, 0, stream>>>(xh_pad, w_g_r, gb, nullptr, gates);
    // ---- r*h into xh_pad high channels ----
    k_pad_tr<1><<<dim3(50, 8, NBB), 256, 0, stream>>>(nodes, gates, xh_pad);
    // ---- cand conv + fused GRU update ----
    k_conv_mfma<1><<<dim3(13, 2, NBB), 256, 0, stream>>>(xh_pad, w_c_r, cb, gates, nodes);
  }
}

// Round 11
// 1428.451 us; speedup vs baseline: 1.2872x; 1.2872x over previous
//
#include <hip/hip_runtime.h>
#include <hip/hip_bf16.h>
#include <math.h>

#define NN 3
#define BB 4
#define CC 256
#define C2 512
#define HH 40
#define WW 40
#define PP 1600
#define NBB 12                  // NN*BB
#define NODESZ (NBB*CC*PP)      // 4,915,200
#define TO 16                   // theta: output channels per block
#define PAD 1764                // 42*42 padded pixels

typedef short short8 __attribute__((ext_vector_type(8)));
typedef float f32x4 __attribute__((ext_vector_type(4)));
typedef unsigned short ushort_t;
typedef unsigned int uint_t;

__device__ __forceinline__ ushort_t f2bf(float x) {
  union { float f; uint_t u; } v; v.f = x;
  uint_t r = v.u + 0x7fff + ((v.u >> 16) & 1);
  return (ushort_t)(r >> 16);
}

__device__ __forceinline__ void async_ld16(const ushort_t* g, ushort_t* l) {
  __builtin_amdgcn_global_load_lds(
      (const __attribute__((address_space(1))) uint_t*)g,
      (__attribute__((address_space(3))) uint_t*)l, 16, 0, 0);
}

__global__ void k_copy(const float* __restrict__ in, float* __restrict__ out) {
  int i = blockIdx.x * 256 + threadIdx.x;
  out[i] = in[i];
}

// th_t[nb][p][c] (bf16) = tb[o] + sum_c tw[o,c] * nodes[nb,c,p]
__global__ void k_theta(const float* __restrict__ nodes, const float* __restrict__ tw,
                        const float* __restrict__ tb, ushort_t* __restrict__ th_t) {
  __shared__ float w[TO * CC];
  int t = threadIdx.x;
  int nb = blockIdx.y / (CC / TO);
  int o0 = (blockIdx.y % (CC / TO)) * TO;
  for (int i = t; i < TO * CC; i += 320) w[i] = tw[(o0 + (i >> 8)) * CC + (i & 255)];
  __syncthreads();
  int p = blockIdx.x * 320 + t;
  const float* src = nodes + nb * CC * PP + p;
  float acc[TO];
#pragma unroll
  for (int o = 0; o < TO; ++o) acc[o] = tb[o0 + o];
  for (int c = 0; c < CC; c += 4) {
    float v0 = src[c * PP], v1 = src[(c + 1) * PP], v2 = src[(c + 2) * PP], v3 = src[(c + 3) * PP];
#pragma unroll
    for (int o = 0; o < TO; ++o) {
      const float4 ww = *(const float4*)(w + o * CC + c);
      acc[o] += ww.x * v0 + ww.y * v1 + ww.z * v2 + ww.w * v3;
    }
  }
  size_t base = ((size_t)nb * PP + p) * CC + o0;
#pragma unroll
  for (int o = 0; o < TO; o += 2) {
    uint_t lo = f2bf(acc[o]), hi = f2bf(acc[o + 1]);
    *(uint_t*)&th_t[base + o] = lo | (hi << 16);
  }
}

// nodes [12][256][1600] fp32 -> nodes_bf_t [12][1600][256] bf16 (transpose),
// with 16B-chunk XOR swizzle within each row: c' = c ^ ((q&7)<<3).
// (Consumed only by k_attn_mfma, which un-XORs on its LDS frag reads.)
__global__ void k_to_bf_t(const float* __restrict__ src, ushort_t* __restrict__ dst) {
  __shared__ float tile[32][33];
  int nb = blockIdx.z;
  int c0 = blockIdx.y * 32;
  int pp0 = blockIdx.x * 32;
  int tx = threadIdx.x & 31, ty = threadIdx.x >> 5;
#pragma unroll
  for (int i = 0; i < 4; ++i)
    tile[ty + 8 * i][tx] = src[((size_t)nb * CC + c0 + ty + 8 * i) * PP + pp0 + tx];
  __syncthreads();
#pragma unroll
  for (int i = 0; i < 4; ++i) {
    int q = pp0 + ty + 8 * i;
    int c = c0 + tx;
    int cs = c ^ ((q & 7) << 3);
    dst[((size_t)nb * PP + q) * CC + cs] = f2bf(tile[tx][ty + 8 * i]);
  }
}

// v_all[e][b][c][p] (bf16) = nodes[recv(e),b,c,p] + nodes[send(e),b,c,p]
__global__ void k_prep_v(const float* __restrict__ nodes, ushort_t* __restrict__ v_all) {
  int i = blockIdx.x * 256 + threadIdx.x;   // 6*4*256*1600
  int eb = i / (CC * PP);
  int rem = i - eb * (CC * PP);
  int e = eb >> 2, b = eb & 3;
  int n = e >> 1, jidx = e & 1;
  int js = jidx + (jidx >= n ? 1 : 0);
  float v = nodes[((size_t)(n * BB + b)) * CC * PP + rem] +
            nodes[((size_t)(js * BB + b)) * CC * PP + rem];
  v_all[i] = f2bf(v);
}

// Hybrid flash attention: 64-p block, 4 waves.
//  - ej q-tile (32 x 256 bf16, 16 KB) staged in LDS, double-buffered, via the
//    proven reg+ds_write pattern (loads issued after barrier A, in flight during
//    S-GEMM/softmax; ds_write after barrier B into the idle buffer).
//  - wave w owns p-rows [16w,16w+16): S-GEMM B-frags from LDS, softmax state in regs.
//  - PV: waves partition channels (64 each); P shared via Sp LDS; alpha via Al LDS.
// Global loads per wave per 32-q iter: 4 staging + 4 V = 8 (r3: 20, r7: 32).
// launch_bounds (256,2): matches the proven r3/r5 config; HW occupancy is
// LDS/VGPR-limited to ~3-4 blocks/CU, enough for all 600 blocks co-resident.
__global__ __launch_bounds__(256, 2) void k_attn_mfma(
    const ushort_t* __restrict__ nodes_bf_t,  // [12][1600][256] chunk-swizzled
    const ushort_t* __restrict__ th_t,        // [12][1600][256] plain
    const ushort_t* __restrict__ v_all,       // [6][4][256][1600]
    float* __restrict__ agg_t)                // [2][12][1600][256]
{
  __shared__ ushort_t Ej[2][32 * 256];   // 2 x 16 KB
  __shared__ ushort_t Sp[64 * 40];       // 5 KB
  __shared__ float Al[64];
  __shared__ float Linv[64];

  const int t = threadIdx.x;
  const int w = t >> 6;
  const int l = t & 63;
  const int quad = l >> 4;
  const int l16 = l & 15;
  const int p0 = blockIdx.x * 64;
  const int nb = blockIdx.y;
  const int jidx = blockIdx.z;
  const int n = nb >> 2, b = nb & 3;
  const int e = n * 2 + jidx;
  const int js = jidx + (jidx >= n ? 1 : 0);

  const ushort_t* thp = th_t + ((size_t)nb * PP + p0) * CC;
  const ushort_t* ejb = nodes_bf_t + ((size_t)(js * BB + b) * PP) * CC;  // [q][c-swz]
  const ushort_t* vp  = v_all + ((size_t)(e * BB + b) * CC) * PP;        // [c][q]

  // resident A-frags of th: wave w rows 16w+l16
  short8 Ath[8];
  {
    const ushort_t* arow = thp + (size_t)(16 * w + l16) * CC + quad * 8;
#pragma unroll
    for (int ks = 0; ks < 8; ++ks) Ath[ks] = *(const short8*)(arow + ks * 32);
  }

  float M[4], L[4];
#pragma unroll
  for (int r = 0; r < 4; ++r) { M[r] = -3.0e38f; L[r] = 0.f; }

  f32x4 O[4][4];
#pragma unroll
  for (int mt = 0; mt < 4; ++mt)
#pragma unroll
    for (int nt = 0; nt < 4; ++nt)
#pragma unroll
      for (int r = 0; r < 4; ++r) O[mt][nt][r] = 0.f;

  // Staging: wave w covers flat shorts [8w*256, 8w*256+4096) of the 32x256 tile
  // (verbatim copy of swizzled global rows q0..q0+31). Chunk i: lanes contiguous
  // 16B each => 1 KB coalesced per instr.
  short8 stg[4];
#pragma unroll
  for (int i = 0; i < 4; ++i)
    stg[i] = *(const short8*)(ejb + (size_t)(8 * w) * CC + i * 512 + l * 8);
#pragma unroll
  for (int i = 0; i < 4; ++i)
    *(short8*)(&Ej[0][8 * w * 256 + i * 512 + l * 8]) = stg[i];
  int buf = 0;

  for (int q0 = 0; q0 < PP; q0 += 32) {
    __syncthreads();   // A: Ej[buf] writes visible; Sp/Al free (prev PV done)
    const bool pf = (q0 + 32 < PP);
    if (pf) {
#pragma unroll
      for (int i = 0; i < 4; ++i)
        stg[i] = *(const short8*)(ejb + (size_t)(q0 + 32 + 8 * w) * CC + i * 512 + l * 8);
    }
    // ---- S-GEMM from LDS: rows 16w+(quad*4+r), cols l16 / 16+l16 ----
    f32x4 S0, S1;
#pragma unroll
    for (int r = 0; r < 4; ++r) { S0[r] = 0.f; S1[r] = 0.f; }
    {
      const ushort_t* ejt = &Ej[buf][0];
#pragma unroll
      for (int ks = 0; ks < 8; ++ks) {
        int ch0 = (((ks * 4 + quad) ^ (l16 & 7)) << 3);
        short8 B0 = *(const short8*)(ejt + l16 * CC + ch0);
        short8 B1 = *(const short8*)(ejt + (16 + l16) * CC + ch0);
        S0 = __builtin_amdgcn_mfma_f32_16x16x32_bf16(Ath[ks], B0, S0, 0, 0, 0);
        S1 = __builtin_amdgcn_mfma_f32_16x16x32_bf16(Ath[ks], B1, S1, 0, 0, 0);
      }
    }
    // ---- in-register online softmax (row = 16w + quad*4 + r) ----
#pragma unroll
    for (int r = 0; r < 4; ++r) {
      float m = fmaxf(S0[r], S1[r]);
      m = fmaxf(m, __shfl_xor(m, 1));
      m = fmaxf(m, __shfl_xor(m, 2));
      m = fmaxf(m, __shfl_xor(m, 4));
      m = fmaxf(m, __shfl_xor(m, 8));
      float Mn = fmaxf(M[r], m);
      float alpha = __expf(M[r] - Mn);
      float e0 = __expf(S0[r] - Mn), e1 = __expf(S1[r] - Mn);
      float s = e0 + e1;
      s += __shfl_xor(s, 1);
      s += __shfl_xor(s, 2);
      s += __shfl_xor(s, 4);
      s += __shfl_xor(s, 8);
      L[r] = L[r] * alpha + s;
      M[r] = Mn;
      int row = 16 * w + quad * 4 + r;
      Sp[row * 40 + l16] = f2bf(e0);
      Sp[row * 40 + 16 + l16] = f2bf(e1);
      if (l16 == 0) Al[row] = alpha;
    }
    __syncthreads();   // B: Sp/Al ready; all waves done reading Ej[buf]
    // ---- stage next tile into Ej[buf^1] (no one reads it until next A) ----
    if (pf) {
#pragma unroll
      for (int i = 0; i < 4; ++i)
        *(short8*)(&Ej[buf ^ 1][8 * w * 256 + i * 512 + l * 8]) = stg[i];
    }
    // ---- rescale O by alpha of its rows ----
#pragma unroll
    for (int mt = 0; mt < 4; ++mt) {
#pragma unroll
      for (int r = 0; r < 4; ++r) {
        float a = Al[16 * mt + quad * 4 + r];
#pragma unroll
        for (int nt = 0; nt < 4; ++nt) O[mt][nt][r] *= a;
      }
    }
    // ---- PV: wave w covers channels [64w,64w+64) ----
    short8 Ap[4], Bv[4];
#pragma unroll
    for (int mt = 0; mt < 4; ++mt)
      Ap[mt] = *(const short8*)(Sp + (16 * mt + l16) * 40 + quad * 8);
    {
      const ushort_t* vrow = vp + (size_t)(64 * w + l16) * PP + q0 + quad * 8;
#pragma unroll
      for (int nt = 0; nt < 4; ++nt)
        Bv[nt] = *(const short8*)(vrow + (size_t)(16 * nt) * PP);
    }
#pragma unroll
    for (int mt = 0; mt < 4; ++mt)
#pragma unroll
      for (int nt = 0; nt < 4; ++nt)
        O[mt][nt] = __builtin_amdgcn_mfma_f32_16x16x32_bf16(Ap[mt], Bv[nt], O[mt][nt], 0, 0, 0);
    buf ^= 1;
  }
  // ---- publish 1/L per row, then epilogue ----
  __syncthreads();
#pragma unroll
  for (int r = 0; r < 4; ++r)
    if (l16 == 0) Linv[16 * w + quad * 4 + r] = 1.f / L[r];
  __syncthreads();
  float* ao = agg_t + (((size_t)jidx * NBB + nb) * PP + p0) * CC;
#pragma unroll
  for (int mt = 0; mt < 4; ++mt) {
#pragma unroll
    for (int r = 0; r < 4; ++r) {
      int m = 16 * mt + quad * 4 + r;
      float inv = Linv[m];
      float* dst = ao + (size_t)m * CC + 64 * w + l16;
#pragma unroll
      for (int nt = 0; nt < 4; ++nt) dst[16 * nt] = O[mt][nt][r] * inv;
    }
  }
}

// ---- conv prep ----

// reorder conv weights [M][512][3][3] fp32 -> [M][9][512] bf16
__global__ void k_wrep(const float* __restrict__ w, ushort_t* __restrict__ wr) {
  int i = blockIdx.x * 256 + threadIdx.x;   // M*9*512
  int ci = i & 511;
  int rest = i >> 9;                        // co*9 + tap
  int tp = rest % 9, co = rest / 9;
  wr[i] = f2bf(w[((size_t)co * 512 + ci) * 9 + tp]);
}

__global__ void k_pad_zero(ushort_t* __restrict__ xpad) {
  int i = blockIdx.x * 256 + threadIdx.x;   // 12*1764*512
  xpad[i] = 0;
}

// interior rows, ch 0..255 <- agg_t[0]+agg_t[1]  (both already [px][c])
__global__ void k_pad_agg(const float* __restrict__ agg_t, ushort_t* __restrict__ xpad) {
  int i = blockIdx.x * 256 + threadIdx.x;   // 12*1600*256
  int c = i & 255;
  int rest = i >> 8;
  int px = rest % PP, nb = rest / PP;
  int y = px / 40, x = px - y * 40;
  size_t src = ((size_t)nb * PP + px) * CC + c;
  float v = agg_t[src] + agg_t[(size_t)NBB * PP * CC + src];
  xpad[((size_t)nb * PAD + (y + 1) * 42 + (x + 1)) * C2 + c] = f2bf(v);
}

// interior rows, ch 256..511 <- transpose of srcA [nb][256][1600]
// MODE 0: val = h[c][px];  MODE 1: val = h[c][px] * r[c][px]
template <int MODE>
__global__ void k_pad_tr(const float* __restrict__ srcA, const float* __restrict__ srcB,
                         ushort_t* __restrict__ xpad) {
  __shared__ float tile[32][33];
  int nb = blockIdx.z;
  int c0 = blockIdx.y * 32;
  int pp0 = blockIdx.x * 32;
  int tx = threadIdx.x & 31, ty = threadIdx.x >> 5;
#pragma unroll
  for (int i = 0; i < 4; ++i) {
    int c = c0 + ty + 8 * i;
    float v = srcA[((size_t)nb * CC + c) * PP + pp0 + tx];
    if (MODE == 1) v *= srcB[((size_t)nb * C2 + c) * PP + pp0 + tx];  // r-gate
    tile[ty + 8 * i][tx] = v;
  }
  __syncthreads();
#pragma unroll
  for (int i = 0; i < 4; ++i) {
    int px = pp0 + ty + 8 * i;
    int y = px / 40, x = px - y * 40;
    xpad[((size_t)nb * PAD + (y + 1) * 42 + (x + 1)) * C2 + CC + c0 + tx] =
        f2bf(tile[tx][ty + 8 * i]);
  }
}

// Implicit-GEMM conv3x3, M=co, N=px(1600), K=9 taps x 512 ci.
// Block: 128co x 128px, 4 waves (2x2), each 64x64 (4x4 16x16x32 frags).
// ACT 0: out = sigmoid(acc+bias) -> gates [nb][512][1600]
// ACT 1: v = tanh(acc+bias); z = zsrc[256+co]; out(nodes) = (1-z)h + z*v
template <int ACT>
__global__ __launch_bounds__(256) void k_conv_mfma(
    const ushort_t* __restrict__ xpad,   // [12][1764][512]
    const ushort_t* __restrict__ wr,     // [M][9*512]
    const float* __restrict__ bias,      // [M]
    const float* __restrict__ zsrc,      // gates (ACT1)
    float* __restrict__ out)
{
  __shared__ ushort_t Asm[128 * 32];
  __shared__ ushort_t Bsm[128 * 32];
  const int t = threadIdx.x;
  const int w = t >> 6, l = t & 63, quad = l >> 4, l16 = l & 15;
  const int nb = blockIdx.z;
  const int m0 = blockIdx.y * 128;
  const int px0 = blockIdx.x * 128;
  const int wm = (w >> 1) * 64, wn = (w & 1) * 64;

  // --- staging source setup (lane l covers rows 32w + l/4 and +16) ---
  const int lr = l >> 2;
  const int swf = (lr ^ (lr >> 2)) & 3;          // fill-side XOR swizzle
  const int lk = ((l & 3) ^ swf) * 8;            // k-part (shorts)
  const ushort_t* wsrc = wr + (size_t)(m0 + 32 * w + lr) * 4608 + lk;
  int pxa = px0 + 32 * w + lr;      if (pxa > 1599) pxa = 1599;
  int pxb = pxa + 16;               if (pxb > 1599) pxb = 1599;
  {
    int d = px0 + 32 * w + 16 + lr; if (d <= 1599) pxb = d;
  }
  const int ya = pxa / 40, xa = pxa - ya * 40;
  const int yb = pxb / 40, xb = pxb - yb * 40;
  const ushort_t* bsrc_a = xpad + ((size_t)nb * PAD + ya * 42 + xa) * C2 + lk;
  const ushort_t* bsrc_b = xpad + ((size_t)nb * PAD + yb * 42 + xb) * C2 + lk;
  ushort_t* Ad0 = Asm + w * 1024;   // wave-uniform LDS base; HW adds lane*16B
  ushort_t* Ad1 = Asm + w * 1024 + 512;
  ushort_t* Bd0 = Bsm + w * 1024;
  ushort_t* Bd1 = Bsm + w * 1024 + 512;

  // --- frag-read swizzle (row&15 == l16 on both A and B) ---
  const int swr = (l16 ^ (l16 >> 2)) & 3;
  const int fk = ((quad ^ swr) * 8);

  f32x4 acc[4][4];
#pragma unroll
  for (int mt = 0; mt < 4; ++mt)
#pragma unroll
    for (int nt = 0; nt < 4; ++nt)
#pragma unroll
      for (int r = 0; r < 4; ++r) acc[mt][nt][r] = 0.f;

  for (int tap = 0; tap < 9; ++tap) {
    const int ky = tap / 3, kx = tap - ky * 3;
    const int boff = (ky * 42 + kx) * C2;
    const ushort_t* wtap = wsrc + tap * 512;
#pragma unroll 1
    for (int c0 = 0; c0 < 512; c0 += 32) {
      __syncthreads();
      async_ld16(wtap + c0, Ad0);
      async_ld16(wtap + 16 * 4608 + c0, Ad1);
      async_ld16(bsrc_a + boff + c0, Bd0);
      async_ld16(bsrc_b + boff + c0, Bd1);
      __syncthreads();
      short8 Af[4], Bf[4];
#pragma unroll
      for (int mt = 0; mt < 4; ++mt)
        Af[mt] = *(const short8*)(Asm + (wm + mt * 16 + l16) * 32 + fk);
#pragma unroll
      for (int nt = 0; nt < 4; ++nt)
        Bf[nt] = *(const short8*)(Bsm + (wn + nt * 16 + l16) * 32 + fk);
#pragma unroll
      for (int mt = 0; mt < 4; ++mt)
#pragma unroll
        for (int nt = 0; nt < 4; ++nt)
          acc[mt][nt] = __builtin_amdgcn_mfma_f32_16x16x32_bf16(Af[mt], Bf[nt], acc[mt][nt], 0, 0, 0);
    }
  }

  // --- epilogue ---
#pragma unroll
  for (int mt = 0; mt < 4; ++mt) {
#pragma unroll
    for (int r = 0; r < 4; ++r) {
      int co = m0 + wm + mt * 16 + quad * 4 + r;
      float bv = bias[co];
#pragma unroll
      for (int nt = 0; nt < 4; ++nt) {
        int px = px0 + wn + nt * 16 + l16;
        if (px >= PP) continue;
        float v = acc[mt][nt][r] + bv;
        if (ACT == 0) {
          out[((size_t)nb * C2 + co) * PP + px] = 1.f / (1.f + __expf(-v));
        } else {
          v = tanhf(v);
          float z = zsrc[((size_t)nb * C2 + CC + co) * PP + px];
          float* hp = out + ((size_t)nb * CC + co) * PP + px;
          float h = *hp;
          *hp = (1.f - z) * h + z * v;
        }
      }
    }
  }
}

extern "C" void kernel_launch(void* const* d_in, const int* in_sizes, int n_in,
                              void* d_out, int out_size, void* d_ws, size_t ws_size,
                              hipStream_t stream) {
  const float* nodes_in = (const float*)d_in[0];
  const float* tw = (const float*)d_in[1];
  const float* tb = (const float*)d_in[2];
  const float* gw = (const float*)d_in[3];
  const float* gb = (const float*)d_in[4];
  const float* cw = (const float*)d_in[5];
  const float* cb = (const float*)d_in[6];

  float* nodes = (float*)d_out;                      // fp32 state [12][256][1600]
  char* ws = (char*)d_ws;
  // ---- layout (ws >= 98.3 MB, proven in round 0/2) ----
  // attn phase: R0 nodes_bf_t 9.83 | R1 th_t 9.83 | R2 v_all 19.66 | R3 agg_t 39.32
  // conv phase: R1+R2 xh_pad 21.68 | R3 gates 39.32
  // persistent:  78.64.. w_g_r 4.72 | 83.36.. w_c_r 2.36   (pass-invariant)
  ushort_t* nodes_bf_t = (ushort_t*)ws;
  ushort_t* th_t  = (ushort_t*)(ws + 9830400);
  ushort_t* v_all = (ushort_t*)(ws + 19660800);
  float*    agg_t = (float*)(ws + 39321600);
  ushort_t* xh_pad = (ushort_t*)(ws + 9830400);      // 12*1764*512*2 = 21,676,032
  float*    gates = (float*)(ws + 39321600);
  ushort_t* w_g_r = (ushort_t*)(ws + 78643200);      // 4,718,592 B
  ushort_t* w_c_r = (ushort_t*)(ws + 83361792);      // 2,359,296 B (ends 85.7 MB)

  k_copy<<<NODESZ / 256, 256, 0, stream>>>(nodes_in, nodes);
  k_wrep<<<(C2 * 9 * C2) / 256, 256, 0, stream>>>(gw, w_g_r);
  k_wrep<<<(CC * 9 * C2) / 256, 256, 0, stream>>>(cw, w_c_r);
  for (int pass = 0; pass < 2; ++pass) {
    // ---- attention ----
    k_theta<<<dim3(5, NBB * (CC / TO)), 320, 0, stream>>>(nodes, tw, tb, th_t);
    k_to_bf_t<<<dim3(50, 8, NBB), 256, 0, stream>>>(nodes, nodes_bf_t);
    k_prep_v<<<(2 * NODESZ) / 256, 256, 0, stream>>>(nodes, v_all);
    k_attn_mfma<<<dim3(25, NBB, 2), 256, 0, stream>>>(nodes_bf_t, th_t, v_all, agg_t);
    // ---- conv prep (attn scratch now dead) ----
    k_pad_zero<<<(NBB * PAD * C2) / 256, 256, 0, stream>>>(xh_pad);
    k_pad_agg<<<(NBB * PP * CC) / 256, 256, 0, stream>>>(agg_t, xh_pad);
    k_pad_tr<0><<<dim3(50, 8, NBB), 256, 0, stream>>>(nodes, nullptr, xh_pad);
    // ---- gates conv ----
    k_conv_mfma<0><<<dim3(13, 4, NBB), 256, 0, stream>>>(xh_pad, w_g_r, gb, nullptr, gates);
    // ---- r*h into xh_pad high channels ----
    k_pad_tr<1><<<dim3(50, 8, NBB), 256, 0, stream>>>(nodes, gates, xh_pad);
    // ---- cand conv + fused GRU update ----
    k_conv_mfma<1><<<dim3(13, 2, NBB), 256, 0, stream>>>(xh_pad, w_c_r, cb, gates, nodes);
  }
}